// Round 1
// baseline (2392.847 us; speedup 1.0000x reference)
//
#include <hip/hip_runtime.h>

#define DIM   128
#define ADIM  6
#define NROWS 1048576
#define NB    8192

// ---------------------------------------------------------------------------
// pass1: stream x_r/x_i (1 GiB), compute 7 dots per row, per-row action
// log_softmax -> d_out, device score -> ws, segment max via keyed atomicMax.
// Layout: 16 lanes per row: q = tid&15, h = q>>3 selects real/imag half,
// c = q&7 selects the 4-float chunk; u=0..3 covers 128 dims (32u + 4c).
// ---------------------------------------------------------------------------
__global__ __launch_bounds__(256) void pass1_kernel(
    const float* __restrict__ x_r, const float* __restrict__ x_i,
    const int* __restrict__ bi,
    const float* __restrict__ Wa_r, const float* __restrict__ Wa_i,
    const float* __restrict__ Wd_r, const float* __restrict__ Wd_i,
    float* __restrict__ out, float* __restrict__ ds_out,
    unsigned int* __restrict__ gmax_key)
{
    const int tid = threadIdx.x;
    const int q = tid & 15;
    const int h = q >> 3;
    const int c = q & 7;

    const float* Wa = h ? Wa_i : Wa_r;
    const float* Wd = h ? Wd_i : Wd_r;

    // 7 outputs x 4 chunks of float4 weights in registers (112 VGPRs)
    float4 w[7][4];
#pragma unroll
    for (int u = 0; u < 4; ++u) {
        const int d = u * 32 + c * 4;
#pragma unroll
        for (int j = 0; j < 6; ++j)
            w[j][u] = *(const float4*)(Wa + j * DIM + d);
        w[6][u] = *(const float4*)(Wd + d);
    }

    const float* xb = h ? x_i : x_r;
    const int rpb = 16;  // rows per block per iteration (256 threads / 16 lanes)

    for (int base = blockIdx.x * rpb; base < NROWS; base += gridDim.x * rpb) {
        const int row = base + (tid >> 4);
        const float* xr = xb + (size_t)row * DIM;

        float s[7] = {0.f, 0.f, 0.f, 0.f, 0.f, 0.f, 0.f};
#pragma unroll
        for (int u = 0; u < 4; ++u) {
            const float4 xv = *(const float4*)(xr + u * 32 + c * 4);
#pragma unroll
            for (int j = 0; j < 7; ++j) {
                s[j] = fmaf(xv.x, w[j][u].x, s[j]);
                s[j] = fmaf(xv.y, w[j][u].y, s[j]);
                s[j] = fmaf(xv.z, w[j][u].z, s[j]);
                s[j] = fmaf(xv.w, w[j][u].w, s[j]);
            }
        }

        // butterfly reduce across the 16-lane group (merges c chunks and r/i halves)
#pragma unroll
        for (int m = 1; m <= 8; m <<= 1) {
#pragma unroll
            for (int j = 0; j < 7; ++j)
                s[j] += __shfl_xor(s[j], m, 64);
        }

        const float inv = 1.0f / (float)DIM;
        float a[6];
#pragma unroll
        for (int j = 0; j < 6; ++j) a[j] = s[j] * inv;
        const float ds = s[6] * inv;

        const float mx = fmaxf(fmaxf(fmaxf(a[0], a[1]), fmaxf(a[2], a[3])),
                               fmaxf(a[4], a[5]));
        float se = 0.f;
#pragma unroll
        for (int j = 0; j < 6; ++j) se += __expf(a[j] - mx);
        const float lse = __logf(se);

        if (q < 6) {
            float v = a[0];
#pragma unroll
            for (int j = 1; j < 6; ++j)
                if (q == j) v = a[j];          // cndmask chain, stays in regs
            out[(size_t)row * ADIM + q] = v - mx - lse;
        } else if (q == 6) {
            ds_out[row] = ds;
        } else {  // q == 7: keyed float atomicMax (exact, order-independent)
            const int seg = bi[row];
            unsigned int b = __float_as_uint(ds);
            unsigned int key = (b & 0x80000000u) ? ~b : (b | 0x80000000u);
            atomicMax(gmax_key + seg, key);
        }
    }
}

__device__ __forceinline__ float unkey(unsigned int k) {
    return __uint_as_float((k & 0x80000000u) ? (k & 0x7FFFFFFFu) : ~k);
}

// ---------------------------------------------------------------------------
// pass2: gsum[seg] = sum exp(ds - gmax[seg]). batch_index is sorted, so do a
// wave-level segmented inclusive scan; one atomicAdd per run boundary.
// ---------------------------------------------------------------------------
__global__ __launch_bounds__(256) void pass2_kernel(
    const float* __restrict__ ds, const int* __restrict__ bi,
    const unsigned int* __restrict__ gmax_key, float* __restrict__ gsum)
{
    const int i = blockIdx.x * 256 + threadIdx.x;
    const int lane = threadIdx.x & 63;
    const float d = ds[i];
    const int seg = bi[i];
    const float gm = unkey(gmax_key[seg]);
    float v = __expf(d - gm);

#pragma unroll
    for (int dd = 1; dd < 64; dd <<= 1) {
        const float ov = __shfl_up(v, dd, 64);
        const int os = __shfl_up(seg, dd, 64);
        if (lane >= dd && os == seg) v += ov;
    }
    const int nseg = __shfl_down(seg, 1, 64);
    if (lane == 63 || nseg != seg)
        atomicAdd(gsum + seg, v);
}

// ---------------------------------------------------------------------------
// pass2b: off[b] = gmax[b] + log(gsum[b])  (empty segments -> NaN, never read)
// ---------------------------------------------------------------------------
__global__ __launch_bounds__(256) void pass2b_kernel(
    const unsigned int* __restrict__ gmax_key, const float* __restrict__ gsum,
    float* __restrict__ off)
{
    const int b = blockIdx.x * 256 + threadIdx.x;
    off[b] = unkey(gmax_key[b]) + __logf(gsum[b]);
}

// ---------------------------------------------------------------------------
// pass3: out[row][j] += ds[row] - off[bi[row]]
// ---------------------------------------------------------------------------
__global__ __launch_bounds__(256) void pass3_kernel(
    float* __restrict__ out, const float* __restrict__ ds,
    const int* __restrict__ bi, const float* __restrict__ off)
{
    const int i = blockIdx.x * 256 + threadIdx.x;   // [0, NROWS*ADIM)
    const int row = i / ADIM;                        // compiler magic-div
    out[i] += ds[row] - off[bi[row]];
}

extern "C" void kernel_launch(void* const* d_in, const int* in_sizes, int n_in,
                              void* d_out, int out_size, void* d_ws, size_t ws_size,
                              hipStream_t stream)
{
    const float* x_r  = (const float*)d_in[0];
    const float* x_i  = (const float*)d_in[1];
    const int*   bi   = (const int*)d_in[2];
    // d_in[3] = state_index: unused by the reference computation
    const float* Wa_r = (const float*)d_in[4];
    const float* Wa_i = (const float*)d_in[5];
    const float* Wd_r = (const float*)d_in[6];
    const float* Wd_i = (const float*)d_in[7];
    float* out = (float*)d_out;

    // workspace layout: ds[N] | gmax_key[B] | gsum[B] | off[B]  (~4.3 MB)
    float*        ds       = (float*)d_ws;
    unsigned int* gmax_key = (unsigned int*)((char*)d_ws + (size_t)NROWS * 4);
    float*        gsum     = (float*)((char*)gmax_key + (size_t)NB * 4);
    float*        off      = (float*)((char*)gsum + (size_t)NB * 4);

    // zero both gmax_key (0 == key below all finite floats) and gsum
    hipMemsetAsync(gmax_key, 0, 2 * (size_t)NB * 4, stream);

    pass1_kernel<<<2048, 256, 0, stream>>>(x_r, x_i, bi, Wa_r, Wa_i,
                                           Wd_r, Wd_i, out, ds, gmax_key);
    pass2_kernel<<<NROWS / 256, 256, 0, stream>>>(ds, bi, gmax_key, gsum);
    pass2b_kernel<<<NB / 256, 256, 0, stream>>>(gmax_key, gsum, off);
    pass3_kernel<<<NROWS * ADIM / 256, 256, 0, stream>>>(out, ds, bi, off);
}

// Round 2
// 1053.981 us; speedup vs baseline: 2.2703x; 2.2703x over previous
//
#include <hip/hip_runtime.h>

#define DIM   128
#define ADIM  6
#define NROWS 1048576
#define NB    8192

#define P1_BLOCKS 1024
#define ROWS_PER_BLOCK_ITER 16   // 4 waves * 4 rows (2 pairs of 2)

// ---------------------------------------------------------------------------
// pass1: stream x_r/x_i (1 GiB), 7 dots per row, per-row action log_softmax
// -> d_out, device score -> ws. NO atomics, NO batch_index read.
// Lane layout (32 lanes per row): q = lane&31, h = q>>4 picks real/imag
// array, c = q&15 picks the float4 chunk; u=0..1 covers 128 dims (64u+4c).
// Weight regs: 7 outputs x 2 chunks x float4 = 56 VGPRs -> stays resident
// under the __launch_bounds__(256,4) cap of 128 VGPRs (round-1 failure mode:
// 112 weight regs were sunk into the loop, re-loading 28x per iteration).
// ---------------------------------------------------------------------------
__global__ __launch_bounds__(256, 4) void pass1_kernel(
    const float* __restrict__ x_r, const float* __restrict__ x_i,
    const float* __restrict__ Wa_r, const float* __restrict__ Wa_i,
    const float* __restrict__ Wd_r, const float* __restrict__ Wd_i,
    float* __restrict__ out, float* __restrict__ ds_out)
{
    const int tid  = threadIdx.x;
    const int wave = tid >> 6;
    const int lane = tid & 63;
    const int rp   = lane >> 5;   // row within the pair (0/1)
    const int q    = lane & 31;
    const int h    = q >> 4;      // 0: real, 1: imag
    const int c    = q & 15;      // float4 chunk

    const float* Wa = h ? Wa_i : Wa_r;
    const float* Wd = h ? Wd_i : Wd_r;

    float4 w[7][2];
#pragma unroll
    for (int u = 0; u < 2; ++u) {
        const int d = u * 64 + c * 4;
#pragma unroll
        for (int j = 0; j < 6; ++j)
            w[j][u] = *(const float4*)(Wa + j * DIM + d);
        w[6][u] = *(const float4*)(Wd + d);
    }

    const float* xb = h ? x_i : x_r;
    const float inv = 1.0f / (float)DIM;

    for (int base = blockIdx.x * ROWS_PER_BLOCK_ITER + wave * 4;
         base < NROWS;
         base += P1_BLOCKS * ROWS_PER_BLOCK_ITER)
    {
        // issue all 4 loads (2 row-pairs x 2 chunks) up front for MLP
        float4 xv[2][2];
#pragma unroll
        for (int p = 0; p < 2; ++p) {
            const float* xr = xb + (size_t)(base + p * 2 + rp) * DIM + c * 4;
            xv[p][0] = *(const float4*)(xr);
            xv[p][1] = *(const float4*)(xr + 64);
        }

        float s[2][7];
#pragma unroll
        for (int p = 0; p < 2; ++p)
#pragma unroll
            for (int j = 0; j < 7; ++j) s[p][j] = 0.f;

#pragma unroll
        for (int p = 0; p < 2; ++p)
#pragma unroll
        for (int u = 0; u < 2; ++u)
#pragma unroll
        for (int j = 0; j < 7; ++j) {
            s[p][j] = fmaf(xv[p][u].x, w[j][u].x, s[p][j]);
            s[p][j] = fmaf(xv[p][u].y, w[j][u].y, s[p][j]);
            s[p][j] = fmaf(xv[p][u].z, w[j][u].z, s[p][j]);
            s[p][j] = fmaf(xv[p][u].w, w[j][u].w, s[p][j]);
        }

        // butterfly reduce across the 32-lane row group (merges chunks + halves)
#pragma unroll
        for (int m = 1; m <= 16; m <<= 1)
#pragma unroll
            for (int p = 0; p < 2; ++p)
#pragma unroll
                for (int j = 0; j < 7; ++j)
                    s[p][j] += __shfl_xor(s[p][j], m, 64);

#pragma unroll
        for (int p = 0; p < 2; ++p) {
            const int row = base + p * 2 + rp;
            float a[6];
#pragma unroll
            for (int j = 0; j < 6; ++j) a[j] = s[p][j] * inv;

            const float mx = fmaxf(fmaxf(fmaxf(a[0], a[1]), fmaxf(a[2], a[3])),
                                   fmaxf(a[4], a[5]));
            float se = 0.f;
#pragma unroll
            for (int j = 0; j < 6; ++j) se += __expf(a[j] - mx);
            const float lse = __logf(se);

            if (q < 6) {
                float v = a[0];
#pragma unroll
                for (int j = 1; j < 6; ++j)
                    if (q == j) v = a[j];      // cndmask chain
                out[(size_t)row * ADIM + q] = v - mx - lse;
            } else if (q == 6) {
                ds_out[row] = s[p][6] * inv;
            }
        }
    }
}

__device__ __forceinline__ unsigned int fkey(float f) {
    unsigned int b = __float_as_uint(f);
    return (b & 0x80000000u) ? ~b : (b | 0x80000000u);
}
__device__ __forceinline__ float unkey(unsigned int k) {
    return __uint_as_float((k & 0x80000000u) ? (k & 0x7FFFFFFFu) : ~k);
}

// ---------------------------------------------------------------------------
// pass_max: segmented max of ds over sorted batch_index via wave-level
// segmented scan; one keyed atomicMax per run boundary (~24K atomics total).
// ---------------------------------------------------------------------------
__global__ __launch_bounds__(256) void pass_max_kernel(
    const float* __restrict__ ds, const int* __restrict__ bi,
    unsigned int* __restrict__ gmax_key)
{
    const int i    = blockIdx.x * 256 + threadIdx.x;
    const int lane = threadIdx.x & 63;
    float v = ds[i];
    const int seg = bi[i];

#pragma unroll
    for (int dd = 1; dd < 64; dd <<= 1) {
        const float ov = __shfl_up(v, dd, 64);
        const int   os = __shfl_up(seg, dd, 64);
        if (lane >= dd && os == seg) v = fmaxf(v, ov);
    }
    const int nseg = __shfl_down(seg, 1, 64);
    if (lane == 63 || nseg != seg)
        atomicMax(gmax_key + seg, fkey(v));
}

// ---------------------------------------------------------------------------
// pass_sum: gsum[seg] = sum exp(ds - gmax[seg]), same segmented-scan scheme.
// ---------------------------------------------------------------------------
__global__ __launch_bounds__(256) void pass_sum_kernel(
    const float* __restrict__ ds, const int* __restrict__ bi,
    const unsigned int* __restrict__ gmax_key, float* __restrict__ gsum)
{
    const int i    = blockIdx.x * 256 + threadIdx.x;
    const int lane = threadIdx.x & 63;
    const float d  = ds[i];
    const int seg  = bi[i];
    float v = __expf(d - unkey(gmax_key[seg]));

#pragma unroll
    for (int dd = 1; dd < 64; dd <<= 1) {
        const float ov = __shfl_up(v, dd, 64);
        const int   os = __shfl_up(seg, dd, 64);
        if (lane >= dd && os == seg) v += ov;
    }
    const int nseg = __shfl_down(seg, 1, 64);
    if (lane == 63 || nseg != seg)
        atomicAdd(gsum + seg, v);
}

// ---------------------------------------------------------------------------
// pass3: out[row][:] += ds[row] - (gmax[seg] + log(gsum[seg])), vectorized
// as float2 (each float2 lies within one row: 2f and 2f+1 straddle a row
// boundary only if 2f % 6 == 5, impossible for even 2f).
// ---------------------------------------------------------------------------
__global__ __launch_bounds__(256) void pass3_kernel(
    float* __restrict__ out, const float* __restrict__ ds,
    const int* __restrict__ bi, const unsigned int* __restrict__ gmax_key,
    const float* __restrict__ gsum)
{
    const unsigned f   = blockIdx.x * 256 + threadIdx.x;  // float2 index
    const unsigned row = f / 3u;                          // 3 float2 per row
    const int seg = bi[row];
    const float off = unkey(gmax_key[seg]) + __logf(gsum[seg]);
    const float add = ds[row] - off;
    float2* o2 = (float2*)out + f;
    float2 v = *o2;
    v.x += add; v.y += add;
    *o2 = v;
}

extern "C" void kernel_launch(void* const* d_in, const int* in_sizes, int n_in,
                              void* d_out, int out_size, void* d_ws, size_t ws_size,
                              hipStream_t stream)
{
    const float* x_r  = (const float*)d_in[0];
    const float* x_i  = (const float*)d_in[1];
    const int*   bi   = (const int*)d_in[2];
    // d_in[3] = state_index: unused by the reference computation
    const float* Wa_r = (const float*)d_in[4];
    const float* Wa_i = (const float*)d_in[5];
    const float* Wd_r = (const float*)d_in[6];
    const float* Wd_i = (const float*)d_in[7];
    float* out = (float*)d_out;

    // workspace: ds[N] | gmax_key[B] | gsum[B]   (~4.3 MB)
    float*        ds       = (float*)d_ws;
    unsigned int* gmax_key = (unsigned int*)((char*)d_ws + (size_t)NROWS * 4);
    float*        gsum     = (float*)((char*)gmax_key + (size_t)NB * 4);

    // zero gmax_key (key 0 < all finite keys) and gsum
    hipMemsetAsync(gmax_key, 0, 2 * (size_t)NB * 4, stream);

    pass1_kernel<<<P1_BLOCKS, 256, 0, stream>>>(x_r, x_i, Wa_r, Wa_i,
                                                Wd_r, Wd_i, out, ds);
    pass_max_kernel<<<NROWS / 256, 256, 0, stream>>>(ds, bi, gmax_key);
    pass_sum_kernel<<<NROWS / 256, 256, 0, stream>>>(ds, bi, gmax_key, gsum);
    pass3_kernel<<<NROWS * 3 / 256, 256, 0, stream>>>(out, ds, bi, gmax_key, gsum);
}